// Round 9
// baseline (123.291 us; speedup 1.0000x reference)
//
#include <hip/hip_runtime.h>
#include <hip/hip_bf16.h>
#include <math.h>

// AKOrN layer: B=2, N=1024, D=256, H=4 (dk=64), O=8, DT=0.1, STEPS=5
// memsetAsync(flags) + ONE kernel.
// Sync ledger (R10-R20): __threadfence ~70us; bulk coherent loads slow;
// atomicAdd-LLC == flag-LLC == dataflow-poll == narrow-flag ~= 7us/exchange
// (mechanism-independent); kernel-per-step worse (~7-8us/boundary, R15);
// sc0 L2-local poll BROKEN on gfx950; XCD-affinity bh=bid&7 works (R19:
// FETCH 10.8->2.1MB, mega4 46.5->42.5, total 119.3). R20 single-kernel with
// monotonic magic flags TRIPPED the determinism check: flags surviving
// across launches == cross-launch state == "branching on call count".
// R21: identical structure, but the 4KB flag region is zeroed per-launch by
// hipMemsetAsync (stream-ordered, graph-capturable) BEFORE k_one. Every
// launch starts from flags=0 -> bit-identical behavior across calls.
// Magic-hi flag encoding kept as defense-in-depth.
//
//   memset : flg[512] u64 = 0 (4KB).
//   k_one  : [proj: stage x+Wk -> K-proj (MFMA) -> Kb; stage Wq+Wp ->
//            Q-proj -> Qs LDS, P-dot -> Psh; wave0 SCb[0]; flag lo=1; wait]
//            -> phase A (scores+exp -> Ush, rowsum) -> 5 Kuramoto steps
//            (flags lo=k+2; step 4 cos-only + 4-producer narrow wait lo=6)
//            -> fused output projection.
//
// Workspace: (unused @0, 1M) | Kb @1M (1M) | SCB @2M+256K (6x256K)
//            flg64 @4M (4KB: u64 per block = (MAGIC<<32)|last-completed)

#define NB 1024
#define NH 4
#define DD 256
#define NO 8
#define SCSZ 131072               // ushorts per SC buffer (256 KB)
#define PI_F      3.14159265358979323846f
#define TWO_PI_F  6.28318530717958647692f
#define INV_2PI_F 0.15915494309189533577f
#define MAGIC_HI  0x9E37A5B3u

typedef __attribute__((ext_vector_type(8))) short bf16x8;
typedef __attribute__((ext_vector_type(4))) float f32x4;
typedef unsigned long long u64;

__device__ __forceinline__ float b2f_u(unsigned short s) {
    union { unsigned u; float f; } x; x.u = ((unsigned)s) << 16; return x.f;
}
__device__ __forceinline__ unsigned short f2b(float f) {
    union { float f; unsigned u; } v; v.f = f;
    unsigned r = v.u + 0x7FFFu + ((v.u >> 16) & 1u);   // RTNE
    return (unsigned short)(r >> 16);
}
__device__ __forceinline__ uint4 load_pack8_rt(int f32v, const void* p, size_t off) {
    if (f32v) {
        const float* fp = (const float*)p + off;
        float4 a = *(const float4*)fp;
        float4 b = *(const float4*)(fp + 4);
        uint4 r;
        r.x = (unsigned)f2b(a.x) | ((unsigned)f2b(a.y) << 16);
        r.y = (unsigned)f2b(a.z) | ((unsigned)f2b(a.w) << 16);
        r.z = (unsigned)f2b(b.x) | ((unsigned)f2b(b.y) << 16);
        r.w = (unsigned)f2b(b.z) | ((unsigned)f2b(b.w) << 16);
        return r;
    }
    return *(const uint4*)((const unsigned short*)p + off);
}
__device__ __forceinline__ void load8_rt(int f32, const void* p, int i, float* f) {
    if (f32) {
        const float* fp = (const float*)p + i;
        float4 a = *(const float4*)fp;
        float4 b = *(const float4*)(fp + 4);
        f[0]=a.x; f[1]=a.y; f[2]=a.z; f[3]=a.w;
        f[4]=b.x; f[5]=b.y; f[6]=b.z; f[7]=b.w;
    } else {
        uint4 u = *(const uint4*)((const unsigned short*)p + i);
        f[0] = b2f_u(u.x & 0xFFFFu); f[1] = b2f_u(u.x >> 16);
        f[2] = b2f_u(u.y & 0xFFFFu); f[3] = b2f_u(u.y >> 16);
        f[4] = b2f_u(u.z & 0xFFFFu); f[5] = b2f_u(u.z >> 16);
        f[6] = b2f_u(u.w & 0xFFFFu); f[7] = b2f_u(u.w >> 16);
    }
}
__device__ __forceinline__ float dot8_bf(uint4 xv, uint4 wv) {
    float r;
    r  = b2f_u((unsigned short)(xv.x & 0xFFFFu)) * b2f_u((unsigned short)(wv.x & 0xFFFFu));
    r += b2f_u((unsigned short)(xv.x >> 16))     * b2f_u((unsigned short)(wv.x >> 16));
    r += b2f_u((unsigned short)(xv.y & 0xFFFFu)) * b2f_u((unsigned short)(wv.y & 0xFFFFu));
    r += b2f_u((unsigned short)(xv.y >> 16))     * b2f_u((unsigned short)(wv.y >> 16));
    r += b2f_u((unsigned short)(xv.z & 0xFFFFu)) * b2f_u((unsigned short)(wv.z & 0xFFFFu));
    r += b2f_u((unsigned short)(xv.z >> 16))     * b2f_u((unsigned short)(wv.z >> 16));
    r += b2f_u((unsigned short)(xv.w & 0xFFFFu)) * b2f_u((unsigned short)(wv.w & 0xFFFFu));
    r += b2f_u((unsigned short)(xv.w >> 16))     * b2f_u((unsigned short)(wv.w >> 16));
    return r;
}
__device__ __forceinline__ float read_cs_bf16(const void* p) {
    float vb = b2f_u(*(const unsigned short*)p);
    bool ok = isfinite(vb) && fabsf(vb) > 1e-30f && fabsf(vb) < 1e30f;
    if (ok) return vb;
    return *(const float*)p;
}
__device__ __forceinline__ int detect_inline(const unsigned short* x) {
    int l = threadIdx.x & 63;
    float a0 = fabsf(b2f_u(x[2 * l]));
    float a1 = fabsf(b2f_u(x[2 * (l + 64)]));
    unsigned long long b0 = __ballot(!(a0 >= 1e-10f && a0 <= 100.0f));
    unsigned long long b1 = __ballot(!(a1 >= 1e-10f && a1 <= 100.0f));
    return (__popcll(b0) + __popcll(b1)) > 16;
}
// agent-scope write-through 8B store (reaches LLC; proven R10-R19)
__device__ __forceinline__ void st8_llc(void* p, u64 v) {
    __hip_atomic_store((u64*)p, v, __ATOMIC_RELAXED, __HIP_MEMORY_SCOPE_AGENT);
}
// Wave-parallel magic-flag wait: valid iff hi==MAGIC_HI && lo>=tgt.
// Flags are zeroed per-launch by hipMemsetAsync -> zero fails the magic
// check -> treated as unwritten. Bounded.
__device__ __forceinline__ void wait_flags_m(const u64* f, unsigned tgt) {
    const int l = threadIdx.x & 63;
    unsigned spins = 0;
    for (;;) {
        u64 v = __hip_atomic_load(f + l, __ATOMIC_RELAXED,
                                  __HIP_MEMORY_SCOPE_AGENT);
        int ok = ((unsigned)(v >> 32) == MAGIC_HI) && ((unsigned)v >= tgt);
        if (__all(ok)) break;
        __builtin_amdgcn_s_sleep(1);
        if (++spins > (1u << 18)) break;               // bounded: cannot hang
    }
}

// ---------------------------------------------------------------------------
// K: everything. Grid 512; bh = bid&7 (XCD affinity, locality only),
// chunk = bid>>3 owns rows [chunk*16, chunk*16+16). cid = bh*64+chunk.
// LDS ~47.3 KB -> >=2 blocks/CU -> all 512 co-resident.
// ---------------------------------------------------------------------------
__global__ __launch_bounds__(256) void k_one(
    const unsigned short* __restrict__ xraw,
    const void* __restrict__ Wq, const void* __restrict__ Wk,
    const void* __restrict__ Wp, const void* __restrict__ bp,
    unsigned short* __restrict__ Kb,
    unsigned short* __restrict__ SCB,
    const void* __restrict__ omega, const void* __restrict__ csp,
    const void* __restrict__ Wo, const void* __restrict__ bo,
    void* __restrict__ out, u64* __restrict__ flg)
{
    __shared__ uint4 Ush[16 * 128];   // 32 KB: Wk stage -> Wq stage -> U tile
    __shared__ f32x4 red[4][64];      // 4 KB: Wp stage -> step reduction
    __shared__ uint4 Xs[16 * 32];     // 8 KB: own x rows, bf16 swizzled
    __shared__ unsigned short Qs[16 * 64];  // 2 KB: own Q rows (x0.125)
    __shared__ float Psh[8 * 16];     // 512 B: own phases [o][localrow]
    __shared__ float redS[4][16];
    __shared__ float Rsh[16];
    __shared__ float sig[4][32];

    const int tid = threadIdx.x;
    const int bid = blockIdx.x;
    const int bh    = bid & 7;          // XCD-affinity grouping
    const int chunk = bid >> 3;
    const int cid   = bh * 64 + chunk;  // flag index, contiguous per bh
    const int i0    = chunk * 16;
    const int h     = bh & 3;
    const int wave = tid >> 6, lane = tid & 63;
    const int n = lane & 15, quad = lane >> 4;
    const int f32 = detect_inline(xraw);

    // ================= projection phase (own rows only) =================
    // stage own x rows (16x256 -> bf16, swizzled) + Wk slice (64x256)
    {
        const size_t xbase = ((size_t)(bh >> 2) * 1024 + i0) * 256;
        #pragma unroll
        for (int g = 0; g < 2; g++) {
            int fidx = g * 256 + tid;                  // 0..511
            int row = fidx >> 5, q = fidx & 31;
            Xs[row * 32 + ((q & 24) | ((q ^ row) & 7))] =
                load_pack8_rt(f32, xraw, xbase + (size_t)row * 256 + q * 8);
        }
        #pragma unroll
        for (int g = 0; g < 8; g++) {
            int fidx = g * 256 + tid;                  // 0..2047
            int row = fidx >> 5, q = fidx & 31;
            Ush[row * 32 + ((q & 24) | ((q ^ row) & 7))] =
                load_pack8_rt(f32, Wk, (size_t)(h * 64 + row) * 256 + q * 8);
        }
    }
    __syncthreads();

    // K-proj: wave w computes feature subtile w*16..w*16+16 for own 16 rows
    {
        f32x4 ka = {0.f, 0.f, 0.f, 0.f};
        #pragma unroll
        for (int s = 0; s < 8; s++) {
            int qc = s * 4 + quad;
            bf16x8 bx = ((const bf16x8*)Xs)[n * 32 + ((qc & 24) | ((qc ^ n) & 7))];
            int wr = wave * 16 + n;
            bf16x8 aw = ((const bf16x8*)Ush)[wr * 32 + ((qc & 24) | ((qc ^ wr) & 7))];
            ka = __builtin_amdgcn_mfma_f32_16x16x32_bf16(aw, bx, ka, 0, 0, 0);
        }
        // lane(n,quad) holds K[i0+n][wave*16+quad*4+r]
        u64 kv = (u64)f2b(ka[0]) | ((u64)f2b(ka[1]) << 16)
               | ((u64)f2b(ka[2]) << 32) | ((u64)f2b(ka[3]) << 48);
        st8_llc(Kb + ((size_t)(bh * NB) + i0 + n) * 64 + wave * 16 + quad * 4, kv);
    }
    __syncthreads();

    // stage Wq slice into Ush (reuse) + Wp slice (8x256) into red[]
    {
        #pragma unroll
        for (int g = 0; g < 8; g++) {
            int fidx = g * 256 + tid;
            int row = fidx >> 5, q = fidx & 31;
            Ush[row * 32 + ((q & 24) | ((q ^ row) & 7))] =
                load_pack8_rt(f32, Wq, (size_t)(h * 64 + row) * 256 + q * 8);
        }
        uint4* wps = (uint4*)red;                      // 256 uint4 = 4 KB
        int row = tid >> 5, q = tid & 31;              // rows 0..7
        wps[row * 32 + q] =
            load_pack8_rt(f32, Wp, (size_t)(h * 8 + row) * 256 + q * 8);
    }
    __syncthreads();

    // Q-proj -> Qs LDS (x0.125); P-dot (VALU) -> Psh[o][row] (+bp)
    {
        f32x4 qa = {0.f, 0.f, 0.f, 0.f};
        #pragma unroll
        for (int s = 0; s < 8; s++) {
            int qc = s * 4 + quad;
            bf16x8 bx = ((const bf16x8*)Xs)[n * 32 + ((qc & 24) | ((qc ^ n) & 7))];
            int wr = wave * 16 + n;
            bf16x8 aw = ((const bf16x8*)Ush)[wr * 32 + ((qc & 24) | ((qc ^ wr) & 7))];
            qa = __builtin_amdgcn_mfma_f32_16x16x32_bf16(aw, bx, qa, 0, 0, 0);
        }
        ushort4 qv = make_ushort4(f2b(qa[0] * 0.125f), f2b(qa[1] * 0.125f),
                                  f2b(qa[2] * 0.125f), f2b(qa[3] * 0.125f));
        *(ushort4*)(Qs + n * 64 + wave * 16 + quad * 4) = qv;

        if (tid < 128) {
            int row = tid >> 3, o = tid & 7;           // local row, oscillator
            float bpv = f32 ? ((const float*)bp)[h * 8 + o]
                            : b2f_u(((const unsigned short*)bp)[h * 8 + o]);
            float accp = bpv;
            const uint4* wps = (const uint4*)red;
            #pragma unroll
            for (int s2 = 0; s2 < 32; s2++) {
                uint4 xv = Xs[row * 32 + ((s2 & 24) | ((s2 ^ row) & 7))];
                accp += dot8_bf(xv, wps[o * 32 + s2]);
            }
            Psh[o * 16 + row] = accp;
        }
    }
    __syncthreads();

    // wave0: pick up phases; write SCb[0] own rows; publish flag lo=1
    float P[4];
    float cs_ = 0.f, om_ = 0.f;
    if (wave == 0 && n < 8) {
        const int o = n;
        cs_ = f32 ? *(const float*)csp : read_cs_bf16(csp);
        om_ = f32 ? ((const float*)omega)[h * NO + o]
                  : b2f_u(((const unsigned short*)omega)[h * NO + o]);
        unsigned short sb[4], cb[4];
        #pragma unroll
        for (int r = 0; r < 4; r++) {
            P[r] = Psh[n * 16 + quad * 4 + r];
            float sn, cn;
            __sincosf(P[r], &sn, &cn);
            sb[r] = f2b(sn); cb[r] = f2b(cn);
        }
        u64 sv = (u64)sb[0] | ((u64)sb[1] << 16) | ((u64)sb[2] << 32) | ((u64)sb[3] << 48);
        u64 cv = (u64)cb[0] | ((u64)cb[1] << 16) | ((u64)cb[2] << 32) | ((u64)cb[3] << 48);
        int i = i0 + quad * 4;
        st8_llc(SCB + (size_t)(bh * 16 + o) * 1024 + i,     sv);
        st8_llc(SCB + (size_t)(bh * 16 + 8 + o) * 1024 + i, cv);
    }
    __syncthreads();   // drains ALL waves' vmcnt: Kb + SCb[0] at LLC
    if (tid == 0) st8_llc(&flg[cid], ((u64)MAGIC_HI << 32) | 1u);
    if (wave == 0) wait_flags_m(flg + bh * 64, 1u);
    __syncthreads();

    // ================= phase A: scores + exp -> Ush, rowsum =================
    bf16x8 bq0 = *(const bf16x8*)(Qs + n * 64 + quad * 8);
    bf16x8 bq1 = *(const bf16x8*)(Qs + n * 64 + 32 + quad * 8);
    float s = 0.f;
    const unsigned short* kbase = Kb + ((size_t)(bh * NB) + n) * 64;
    #pragma unroll
    for (int t = 0; t < 16; t++) {
        int jt = wave * 16 + t;                       // j-tile 0..63
        const unsigned short* arow = kbase + (size_t)jt * 16 * 64;
        bf16x8 a0 = *(const bf16x8*)(arow + quad * 8);
        bf16x8 a1 = *(const bf16x8*)(arow + 32 + quad * 8);
        f32x4 acc = {0.f, 0.f, 0.f, 0.f};
        acc = __builtin_amdgcn_mfma_f32_16x16x32_bf16(a0, bq0, acc, 0, 0, 0);
        acc = __builtin_amdgcn_mfma_f32_16x16x32_bf16(a1, bq1, acc, 0, 0, 0);
        float u0 = __expf(acc[0]);
        float u1 = __expf(acc[1]);
        float u2 = __expf(acc[2]);
        float u3 = __expf(acc[3]);
        s += (u0 + u1) + (u2 + u3);
        ushort4 uv = make_ushort4(f2b(u0), f2b(u1), f2b(u2), f2b(u3));
        int cw = 2 * jt + (quad >> 1);
        ((ushort4*)Ush)[(n * 128 + (cw ^ (n & 7))) * 2 + (quad & 1)] = uv;
    }
    s += __shfl_xor(s, 16);
    s += __shfl_xor(s, 32);
    if (lane < 16) redS[wave][lane] = s;
    __syncthreads();
    if (tid < 16)
        Rsh[tid] = 1.0f / (redS[0][tid] + redS[1][tid] + redS[2][tid] + redS[3][tid]);

    // ================= 5 steps; SCb[k] -> SCb[k+1] =================
    #pragma unroll 1
    for (int k = 0; k < 5; k++) {
        const unsigned short* scrow = SCB + (size_t)k * SCSZ + (size_t)(bh * 16 + n) * 1024;
        unsigned short* scout       = SCB + (size_t)(k + 1) * SCSZ;
        f32x4 acc = {0.f, 0.f, 0.f, 0.f};
        #pragma unroll
        for (int t = 0; t < 8; t++) {
            int it = wave * 8 + t;
            bf16x8 a = ((const bf16x8*)Ush)[n * 128 + ((it * 4 + quad) ^ (n & 7))];
            bf16x8 b = *(const bf16x8*)(scrow + it * 32 + quad * 8);  // normal b128
            acc = __builtin_amdgcn_mfma_f32_16x16x32_bf16(a, b, acc, 0, 0, 0);
        }
        red[wave][lane] = acc;
        __syncthreads();

        if (wave == 0) {
            f32x4 a0 = red[0][lane], a1 = red[1][lane];
            f32x4 a2 = red[2][lane], a3 = red[3][lane];
            #pragma unroll
            for (int v = 0; v < 4; v++) acc[v] = (a0[v] + a1[v]) + (a2[v] + a3[v]);
            float C0 = __shfl_xor(acc[0], 8);
            float C1 = __shfl_xor(acc[1], 8);
            float C2 = __shfl_xor(acc[2], 8);
            float C3 = __shfl_xor(acc[3], 8);
            if (n < 8) {
                const int o = n;
                float S[4] = {acc[0], acc[1], acc[2], acc[3]};
                float C[4] = {C0, C1, C2, C3};
                float Rr[4] = {Rsh[quad * 4], Rsh[quad * 4 + 1],
                               Rsh[quad * 4 + 2], Rsh[quad * 4 + 3]};
                unsigned short sb[4], cb[4];
                #pragma unroll
                for (int r = 0; r < 4; r++) {
                    float si, ci;
                    __sincosf(P[r], &si, &ci);
                    float coup = (ci * S[r] - si * C[r]) * Rr[r];
                    float v = P[r] + 0.1f * (om_ + cs_ * coup);
                    float t2 = v + PI_F;
                    t2 -= floorf(t2 * INV_2PI_F) * TWO_PI_F;   // jnp.remainder
                    P[r] = t2 - PI_F;
                    float sn, cn;
                    __sincosf(P[r], &sn, &cn);
                    sb[r] = f2b(sn); cb[r] = f2b(cn);
                }
                u64 sv = (u64)sb[0] | ((u64)sb[1] << 16) | ((u64)sb[2] << 32) | ((u64)sb[3] << 48);
                u64 cv = (u64)cb[0] | ((u64)cb[1] << 16) | ((u64)cb[2] << 32) | ((u64)cb[3] << 48);
                int i = i0 + quad * 4;
                if (k < 4)                      // sin unused after step 4
                    st8_llc(scout + (size_t)(bh * 16 + o) * 1024 + i, sv);
                st8_llc(scout + (size_t)(bh * 16 + 8 + o) * 1024 + i, cv);
            }
        }
        __syncthreads();   // drains wave0's data stores before the signal
        if (tid == 0) st8_llc(&flg[cid], ((u64)MAGIC_HI << 32) | (u64)(k + 2));
        if (k < 4) {
            if (wave == 0) wait_flags_m(flg + bh * 64, (unsigned)(k + 2));
        } else {
            // wait on the 4 producers of this block's output rows
            const int ob = bh >> 2;
            const int jc = (chunk >> 2) + 16 * (bh & 3);
            if (wave == 0) {
                unsigned spins = 0;
                for (;;) {
                    int ok = 1;
                    if (lane < 4) {
                        u64 v = __hip_atomic_load(
                            &flg[(ob * 4 + lane) * 64 + jc],
                            __ATOMIC_RELAXED, __HIP_MEMORY_SCOPE_AGENT);
                        ok = ((unsigned)(v >> 32) == MAGIC_HI) && ((unsigned)v >= 6u);
                    }
                    if (__all(ok)) break;
                    __builtin_amdgcn_s_sleep(1);
                    if (++spins > (1u << 18)) break;   // bounded: cannot hang
                }
            }
        }
        __syncthreads();
    }

    // ======= fused output projection: (b = bh>>2, rows n0..n0+3) =======
    const unsigned short* scfin = SCB + (size_t)5 * SCSZ;
    const int ob = bh >> 2;
    const int n0 = (chunk | ((bh & 3) << 6)) * 4;      // bijection over batch
    if (tid < 32) {
        int h2 = tid >> 3, o = tid & 7;
        // normal load: this block never read SCb[5] before -> cannot be stale
        u64 q = *(const u64*)(scfin + (size_t)((ob * NH + h2) * 16 + 8 + o) * 1024 + n0);
        #pragma unroll
        for (int r = 0; r < 4; r++)
            sig[r][tid] = b2f_u((unsigned short)(q >> (16 * r)));
    }
    __syncthreads();
    float wv[32];
    #pragma unroll
    for (int d0 = 0; d0 < 32; d0 += 8) load8_rt(f32, Wo, tid * 32 + d0, wv + d0);
    const float bov = f32 ? ((const float*)bo)[tid] : b2f_u(((const unsigned short*)bo)[tid]);
    #pragma unroll
    for (int r = 0; r < 4; r++) {
        float acc = bov;
        #pragma unroll
        for (int t = 0; t < 32; t++) acc += sig[r][t] * wv[t];
        size_t oi = ((size_t)ob * 1024 + n0 + r) * DD + tid;
        if (f32) ((float*)out)[oi] = acc;
        else     ((unsigned short*)out)[oi] = f2b(acc);
    }
}

// ---------------------------------------------------------------------------
extern "C" void kernel_launch(void* const* d_in, const int* in_sizes, int n_in,
                              void* d_out, int out_size, void* d_ws, size_t ws_size,
                              hipStream_t stream)
{
    const unsigned short* x = (const unsigned short*)d_in[0];
    const void* Wq  = d_in[1];
    const void* Wk  = d_in[2];
    const void* Wp  = d_in[3];
    const void* bp  = d_in[4];
    const void* Wo  = d_in[5];
    const void* bo  = d_in[6];
    const void* om  = d_in[7];
    const void* cs  = d_in[8];

    char* w = (char*)d_ws;
    unsigned short* Kb  = (unsigned short*)(w + (1u << 20));
    unsigned short* SCB = (unsigned short*)(w + (2u << 20) + (256u << 10));
    u64*            flg = (u64*)(w + (4u << 20));

    // Per-launch flag reset: stream-ordered, graph-capturable. Restores the
    // "flags start at 0" invariant every call -> deterministic across calls.
    hipMemsetAsync(flg, 0, 512 * sizeof(u64), stream);
    k_one<<<512, 256, 0, stream>>>(x, Wq, Wk, Wp, bp, Kb, SCB, om, cs,
                                   Wo, bo, d_out, flg);
}

// Round 10
// 119.208 us; speedup vs baseline: 1.0342x; 1.0342x over previous
//
#include <hip/hip_runtime.h>
#include <hip/hip_bf16.h>
#include <math.h>

// AKOrN layer: B=2, N=1024, D=256, H=4 (dk=64), O=8, DT=0.1, STEPS=5
// TWO plain launches.  == R19 configuration, best measured: 119.3us ==
// Ledger (R10-R21): __threadfence ~70us; bulk coherent loads slow;
// atomicAdd-LLC == flag-LLC == dataflow-poll == narrow-flag ~= 7us/exchange
// (mechanism-independent -> 4-exchange floor ~28us structural);
// kernel-per-step worse (~7-8us/boundary, R15); sc0 L2-local poll BROKEN on
// gfx950 (85ms timeout); wave0-serialized signal+wait worse with fused
// output (R18); single-kernel fold worse (R21: k_one 69.5us -- redundant
// per-block W staging + 4x bank conflicts + first-exchange dispatch skew);
// replication priced out (~42us L2-BW). R19's three wins kept:
//   (1) full-block barrier form (the measured-46.5 one);
//   (2) XCD-affinity bh = bid&7: each bh's Kb read by ~one XCD -> L2 dedup
//       (FETCH 10.8->2.1MB, mega4 46.5->42.5);
//   (3) step 4 stores cos only + waits on only the 4 producer flags of its
//       output rows.
//
//   k_projm : zeroes flags; dtype-detect + bf16 cvt; MFMA GEMM -> Qb(x0.125),
//             Kb, PH0 fp32 [bh][o][n], SCb[0] bf16 sin/cos.
//   k_mega4 : scores+exp -> U in LDS, rowsum -> Rsh; 5 Kuramoto steps
//             (phases in wave-0 regs; SCb[k] -> SCb[k+1]; per-bh flag
//             barrier, step-4 cos-only + 4-flag producer wait); fused
//             output projection.
//
// Workspace: Qb @0 (1M) | Kb @1M (1M) | PH0 @2M (256K) | SCB @2M+256K (6x256K)
//            flags @4M (2KB: flg[bh*64+chunk] = last completed step)

#define NB 1024
#define NH 4
#define DD 256
#define NO 8
#define SCSZ 131072               // ushorts per SC buffer (256 KB)
#define PI_F      3.14159265358979323846f
#define TWO_PI_F  6.28318530717958647692f
#define INV_2PI_F 0.15915494309189533577f

typedef __attribute__((ext_vector_type(8))) short bf16x8;
typedef __attribute__((ext_vector_type(4))) float f32x4;
typedef unsigned long long u64;

__device__ __forceinline__ float b2f_u(unsigned short s) {
    union { unsigned u; float f; } x; x.u = ((unsigned)s) << 16; return x.f;
}
__device__ __forceinline__ unsigned short f2b(float f) {
    union { float f; unsigned u; } v; v.f = f;
    unsigned r = v.u + 0x7FFFu + ((v.u >> 16) & 1u);   // RTNE
    return (unsigned short)(r >> 16);
}
template<bool F32>
__device__ __forceinline__ uint4 load_pack8(const void* p, size_t off) {
    if (!F32) return *(const uint4*)((const unsigned short*)p + off);
    const float* fp = (const float*)p + off;
    float4 a = *(const float4*)fp;
    float4 b = *(const float4*)(fp + 4);
    uint4 r;
    r.x = (unsigned)f2b(a.x) | ((unsigned)f2b(a.y) << 16);
    r.y = (unsigned)f2b(a.z) | ((unsigned)f2b(a.w) << 16);
    r.z = (unsigned)f2b(b.x) | ((unsigned)f2b(b.y) << 16);
    r.w = (unsigned)f2b(b.z) | ((unsigned)f2b(b.w) << 16);
    return r;
}
__device__ __forceinline__ void load8_rt(int f32, const void* p, int i, float* f) {
    if (f32) {
        const float* fp = (const float*)p + i;
        float4 a = *(const float4*)fp;
        float4 b = *(const float4*)(fp + 4);
        f[0]=a.x; f[1]=a.y; f[2]=a.z; f[3]=a.w;
        f[4]=b.x; f[5]=b.y; f[6]=b.z; f[7]=b.w;
    } else {
        uint4 u = *(const uint4*)((const unsigned short*)p + i);
        f[0] = b2f_u(u.x & 0xFFFFu); f[1] = b2f_u(u.x >> 16);
        f[2] = b2f_u(u.y & 0xFFFFu); f[3] = b2f_u(u.y >> 16);
        f[4] = b2f_u(u.z & 0xFFFFu); f[5] = b2f_u(u.z >> 16);
        f[6] = b2f_u(u.w & 0xFFFFu); f[7] = b2f_u(u.w >> 16);
    }
}
__device__ __forceinline__ float read_cs_bf16(const void* p) {
    float vb = b2f_u(*(const unsigned short*)p);
    bool ok = isfinite(vb) && fabsf(vb) > 1e-30f && fabsf(vb) < 1e30f;
    if (ok) return vb;
    return *(const float*)p;
}
__device__ __forceinline__ int detect_inline(const unsigned short* x) {
    int l = threadIdx.x & 63;
    float a0 = fabsf(b2f_u(x[2 * l]));
    float a1 = fabsf(b2f_u(x[2 * (l + 64)]));
    unsigned long long b0 = __ballot(!(a0 >= 1e-10f && a0 <= 100.0f));
    unsigned long long b1 = __ballot(!(a1 >= 1e-10f && a1 <= 100.0f));
    return (__popcll(b0) + __popcll(b1)) > 16;
}
// agent-scope write-through stores (reach LLC; proven R10/R11/R12)
__device__ __forceinline__ void st8_llc(void* p, u64 v) {
    __hip_atomic_store((u64*)p, v, __ATOMIC_RELAXED, __HIP_MEMORY_SCOPE_AGENT);
}
__device__ __forceinline__ void st4_llc(unsigned* p, unsigned v) {
    __hip_atomic_store(p, v, __ATOMIC_RELAXED, __HIP_MEMORY_SCOPE_AGENT);
}
// Wave-parallel agent-scope flag wait (LLC). Bounded: cannot hang.
__device__ __forceinline__ void wait_flags64(const unsigned* f, unsigned tgt) {
    const int l = threadIdx.x & 63;
    unsigned spins = 0;
    for (;;) {
        unsigned v = __hip_atomic_load(f + l, __ATOMIC_RELAXED,
                                       __HIP_MEMORY_SCOPE_AGENT);
        if (__all((int)(v >= tgt))) break;
        __builtin_amdgcn_s_sleep(1);
        if (++spins > (1u << 18)) break;
    }
}

// ---------------------------------------------------------------------------
// K1: MFMA projection GEMM. Grid 288 = 32 i x 9 f. ftile 0-3 -> Qb(x0.125),
// 4-7 -> Kb, 8 -> PH0(+bp) + SCb[0]. Block 0 zeroes the flag array.
// ---------------------------------------------------------------------------
template<bool F32>
__device__ void projm_impl(
    const void* __restrict__ x, const void* __restrict__ Wq,
    const void* __restrict__ Wk, const void* __restrict__ Wp,
    const void* __restrict__ bp,
    unsigned short* __restrict__ Qb, unsigned short* __restrict__ Kb,
    float* __restrict__ PH, unsigned short* __restrict__ SC)
{
    __shared__ uint4 Xsh[64 * 32];   // 32 KB
    __shared__ uint4 Wsh[64 * 32];   // 32 KB
    const int tid = threadIdx.x;
    const int ftile = blockIdx.x % 9, itile = blockIdx.x / 9;
    const int i0 = itile * 64, f0 = ftile * 64;
    const int wave = tid >> 6, lane = tid & 63;
    const int n = lane & 15, quad = lane >> 4;

    #pragma unroll
    for (int g = 0; g < 8; g++) {
        int fidx = g * 256 + tid;
        int row = fidx >> 5, q = fidx & 31;
        int sw = (q & 24) | ((q ^ row) & 7);
        Xsh[row * 32 + sw] = load_pack8<F32>(x, (size_t)(i0 + row) * 256 + q * 8);
        int wr = f0 + row;
        uint4 wv = make_uint4(0, 0, 0, 0);
        if (wr < 256)      wv = load_pack8<F32>(Wq, (size_t)wr * 256 + q * 8);
        else if (wr < 512) wv = load_pack8<F32>(Wk, (size_t)(wr - 256) * 256 + q * 8);
        else if (wr < 544) wv = load_pack8<F32>(Wp, (size_t)(wr - 512) * 256 + q * 8);
        Wsh[row * 32 + sw] = wv;
    }
    __syncthreads();

    f32x4 acc[4];
    #pragma unroll
    for (int s = 0; s < 4; s++) acc[s] = (f32x4){0.f, 0.f, 0.f, 0.f};
    const int xrow = wave * 16 + n;
    #pragma unroll
    for (int s = 0; s < 8; s++) {
        int qc = s * 4 + quad;
        bf16x8 b = ((const bf16x8*)Xsh)[xrow * 32 + ((qc & 24) | ((qc ^ xrow) & 7))];
        #pragma unroll
        for (int sub = 0; sub < 4; sub++) {
            int wr = sub * 16 + n;
            bf16x8 a = ((const bf16x8*)Wsh)[wr * 32 + ((qc & 24) | ((qc ^ wr) & 7))];
            acc[sub] = __builtin_amdgcn_mfma_f32_16x16x32_bf16(a, b, acc[sub], 0, 0, 0);
        }
    }

    const int ig = i0 + wave * 16 + n;
    const int bb = ig >> 10, nr = ig & 1023;
    if (ftile < 4) {
        #pragma unroll
        for (int sub = 0; sub < 4; sub++) {
            int dd = sub * 16 + quad * 4;
            ushort4 v = make_ushort4(f2b(acc[sub][0] * 0.125f), f2b(acc[sub][1] * 0.125f),
                                     f2b(acc[sub][2] * 0.125f), f2b(acc[sub][3] * 0.125f));
            *(ushort4*)(Qb + ((size_t)((bb * NH + ftile) * NB + nr)) * 64 + dd) = v;
        }
    } else if (ftile < 8) {
        int h = ftile - 4;
        #pragma unroll
        for (int sub = 0; sub < 4; sub++) {
            int dd = sub * 16 + quad * 4;
            ushort4 v = make_ushort4(f2b(acc[sub][0]), f2b(acc[sub][1]),
                                     f2b(acc[sub][2]), f2b(acc[sub][3]));
            *(ushort4*)(Kb + ((size_t)((bb * NH + h) * NB + nr)) * 64 + dd) = v;
        }
    } else {
        #pragma unroll
        for (int sub = 0; sub < 2; sub++) {
            #pragma unroll
            for (int r = 0; r < 4; r++) {
                int fp = sub * 16 + quad * 4 + r;       // 0..31
                int h2 = fp >> 3, o = fp & 7;
                float bpv = F32 ? ((const float*)bp)[fp]
                                : b2f_u(((const unsigned short*)bp)[fp]);
                float v = acc[sub][r] + bpv;
                int bh = bb * NH + h2;
                PH[(size_t)bh * 8192 + o * 1024 + nr] = v;
                float sv, cv;
                __sincosf(v, &sv, &cv);
                SC[(size_t)(bh * 16 + o) * 1024 + nr]     = f2b(sv);
                SC[(size_t)(bh * 16 + 8 + o) * 1024 + nr] = f2b(cv);
            }
        }
    }
}

__global__ __launch_bounds__(256) void k_projm(
    const unsigned short* x, const void* Wq, const void* Wk, const void* Wp,
    const void* bp, unsigned short* Qb, unsigned short* Kb, float* PH,
    unsigned short* SC, unsigned int* flg)
{
    if (blockIdx.x == 0) {
        flg[threadIdx.x] = 0u;          // 512 flags: flg[bh*64+chunk]
        flg[threadIdx.x + 256] = 0u;
    }
    if (detect_inline(x)) projm_impl<true >(x, Wq, Wk, Wp, bp, Qb, Kb, PH, SC);
    else                  projm_impl<false>(x, Wq, Wk, Wp, bp, Qb, Kb, PH, SC);
}

// ---------------------------------------------------------------------------
// K2: mega kernel. Grid 512; bh = bid&7 (XCD affinity under round-robin
// dispatch: each bh's Kb reads stay on ~one XCD L2 -- locality heuristic
// only, correctness never depends on it), chunk = bid>>3 owns rows
// [chunk*16, chunk*16+16). Flag index cid = bh*64+chunk (contiguous per bh).
// Barrier form = round-0 proven: __syncthreads; tid0 signal; wave0 wait;
// __syncthreads. Step 4: cos-only stores, wait on 4 producer flags of this
// block's output rows, then fused output projection.
// ---------------------------------------------------------------------------
__global__ __launch_bounds__(256) void k_mega4(
    const unsigned short* __restrict__ xraw,
    const unsigned short* __restrict__ Qb, const unsigned short* __restrict__ Kb,
    const float* __restrict__ PH0,
    unsigned short* __restrict__ SCB,
    const void* __restrict__ omega, const void* __restrict__ csp,
    const void* __restrict__ Wo, const void* __restrict__ bo,
    void* __restrict__ out, unsigned int* __restrict__ flg)
{
    __shared__ uint4 Ush[16 * 128];   // 32 KB block-private U tile
    __shared__ f32x4 red[4][64];      // 4 KB
    __shared__ float redS[4][16];
    __shared__ float Rsh[16];
    __shared__ float sig[4][32];

    const int tid = threadIdx.x;
    const int bid = blockIdx.x;
    const int bh    = bid & 7;          // XCD-affinity grouping
    const int chunk = bid >> 3;
    const int cid   = bh * 64 + chunk;  // flag index, contiguous per bh
    const int i0    = chunk * 16;
    const int wave = tid >> 6, lane = tid & 63;
    const int n = lane & 15, quad = lane >> 4;
    const int f32 = detect_inline(xraw);

    // ---- phase A: scores + exp -> Ush (LDS only), rowsum -> Rsh ----
    const unsigned short* qrow = Qb + ((size_t)(bh * NB) + i0 + n) * 64;
    bf16x8 bq0 = *(const bf16x8*)(qrow + quad * 8);
    bf16x8 bq1 = *(const bf16x8*)(qrow + 32 + quad * 8);
    float s = 0.f;
    const unsigned short* kbase = Kb + ((size_t)(bh * NB) + n) * 64;
    #pragma unroll
    for (int t = 0; t < 16; t++) {
        int jt = wave * 16 + t;                       // j-tile 0..63
        const unsigned short* arow = kbase + (size_t)jt * 16 * 64;
        bf16x8 a0 = *(const bf16x8*)(arow + quad * 8);
        bf16x8 a1 = *(const bf16x8*)(arow + 32 + quad * 8);
        f32x4 acc = {0.f, 0.f, 0.f, 0.f};
        acc = __builtin_amdgcn_mfma_f32_16x16x32_bf16(a0, bq0, acc, 0, 0, 0);
        acc = __builtin_amdgcn_mfma_f32_16x16x32_bf16(a1, bq1, acc, 0, 0, 0);
        float u0 = __expf(acc[0]);
        float u1 = __expf(acc[1]);
        float u2 = __expf(acc[2]);
        float u3 = __expf(acc[3]);
        s += (u0 + u1) + (u2 + u3);
        ushort4 uv = make_ushort4(f2b(u0), f2b(u1), f2b(u2), f2b(u3));
        int cw = 2 * jt + (quad >> 1);
        ((ushort4*)Ush)[(n * 128 + (cw ^ (n & 7))) * 2 + (quad & 1)] = uv;
    }
    s += __shfl_xor(s, 16);
    s += __shfl_xor(s, 32);
    if (lane < 16) redS[wave][lane] = s;
    __syncthreads();
    if (tid < 16)
        Rsh[tid] = 1.0f / (redS[0][tid] + redS[1][tid] + redS[2][tid] + redS[3][tid]);

    // ---- wave-0 persistent oscillator state ----
    float P[4];
    float cs_ = 0.f, om_ = 0.f;
    if (wave == 0 && n < 8) {
        const int o = n, h = bh & 3;
        cs_ = f32 ? *(const float*)csp : read_cs_bf16(csp);
        om_ = f32 ? ((const float*)omega)[h * NO + o]
                  : b2f_u(((const unsigned short*)omega)[h * NO + o]);
        float4 pv = *(const float4*)(PH0 + (size_t)bh * 8192 + o * 1024 + i0 + quad * 4);
        P[0] = pv.x; P[1] = pv.y; P[2] = pv.z; P[3] = pv.w;
    }

    // ---- 5 steps; SCb[k] -> SCb[k+1]; round-0 barrier form ----
    #pragma unroll 1
    for (int k = 0; k < 5; k++) {
        const unsigned short* scrow = SCB + (size_t)k * SCSZ + (size_t)(bh * 16 + n) * 1024;
        unsigned short* scout       = SCB + (size_t)(k + 1) * SCSZ;
        f32x4 acc = {0.f, 0.f, 0.f, 0.f};
        #pragma unroll
        for (int t = 0; t < 8; t++) {
            int it = wave * 8 + t;
            bf16x8 a = ((const bf16x8*)Ush)[n * 128 + ((it * 4 + quad) ^ (n & 7))];
            bf16x8 b = *(const bf16x8*)(scrow + it * 32 + quad * 8);  // normal b128
            acc = __builtin_amdgcn_mfma_f32_16x16x32_bf16(a, b, acc, 0, 0, 0);
        }
        red[wave][lane] = acc;
        __syncthreads();

        if (wave == 0) {
            f32x4 a0 = red[0][lane], a1 = red[1][lane];
            f32x4 a2 = red[2][lane], a3 = red[3][lane];
            #pragma unroll
            for (int v = 0; v < 4; v++) acc[v] = (a0[v] + a1[v]) + (a2[v] + a3[v]);
            float C0 = __shfl_xor(acc[0], 8);
            float C1 = __shfl_xor(acc[1], 8);
            float C2 = __shfl_xor(acc[2], 8);
            float C3 = __shfl_xor(acc[3], 8);
            if (n < 8) {
                const int o = n;
                float S[4] = {acc[0], acc[1], acc[2], acc[3]};
                float C[4] = {C0, C1, C2, C3};
                float Rr[4] = {Rsh[quad * 4], Rsh[quad * 4 + 1],
                               Rsh[quad * 4 + 2], Rsh[quad * 4 + 3]};
                unsigned short sb[4], cb[4];
                #pragma unroll
                for (int r = 0; r < 4; r++) {
                    float si, ci;
                    __sincosf(P[r], &si, &ci);
                    float coup = (ci * S[r] - si * C[r]) * Rr[r];
                    float v = P[r] + 0.1f * (om_ + cs_ * coup);
                    float t2 = v + PI_F;
                    t2 -= floorf(t2 * INV_2PI_F) * TWO_PI_F;   // jnp.remainder
                    P[r] = t2 - PI_F;
                    float sn, cn;
                    __sincosf(P[r], &sn, &cn);
                    sb[r] = f2b(sn); cb[r] = f2b(cn);
                }
                u64 sv = (u64)sb[0] | ((u64)sb[1] << 16) | ((u64)sb[2] << 32) | ((u64)sb[3] << 48);
                u64 cv = (u64)cb[0] | ((u64)cb[1] << 16) | ((u64)cb[2] << 32) | ((u64)cb[3] << 48);
                int i = i0 + quad * 4;
                if (k < 4)                      // sin unused after step 4
                    st8_llc(scout + (size_t)(bh * 16 + o) * 1024 + i, sv);
                st8_llc(scout + (size_t)(bh * 16 + 8 + o) * 1024 + i, cv);
            }
        }
        __syncthreads();   // per-wave vmcnt drain: stores at LLC before signal
        if (tid == 0) st4_llc(&flg[cid], (unsigned)(k + 1));
        if (k < 4) {
            if (wave == 0) wait_flags64(flg + bh * 64, (unsigned)(k + 1));
        } else {
            // wait on the 4 producers of this block's output rows:
            // rows n0..n0+3 live in 16-row chunk jc of each head ob*4+h
            const int ob = bh >> 2;
            const int jc = (chunk >> 2) + 16 * (bh & 3);
            if (wave == 0) {
                unsigned spins = 0;
                for (;;) {
                    int ok = 1;
                    if (lane < 4) {
                        unsigned v = __hip_atomic_load(
                            &flg[(ob * 4 + lane) * 64 + jc],
                            __ATOMIC_RELAXED, __HIP_MEMORY_SCOPE_AGENT);
                        ok = (v >= 5u);
                    }
                    if (__all(ok)) break;
                    __builtin_amdgcn_s_sleep(1);
                    if (++spins > (1u << 18)) break;   // bounded: cannot hang
                }
            }
        }
        __syncthreads();
    }

    // ---- fused output projection: (b = bh>>2, rows n0..n0+3) ----
    const unsigned short* scfin = SCB + (size_t)5 * SCSZ;
    const int ob = bh >> 2;
    const int n0 = (chunk | ((bh & 3) << 6)) * 4;      // bijection over batch
    if (tid < 32) {
        int h = tid >> 3, o = tid & 7;
        // normal load: this block never read SCb[5] before -> cannot be stale
        u64 q = *(const u64*)(scfin + (size_t)((ob * NH + h) * 16 + 8 + o) * 1024 + n0);
        #pragma unroll
        for (int r = 0; r < 4; r++)
            sig[r][tid] = b2f_u((unsigned short)(q >> (16 * r)));
    }
    __syncthreads();
    float wv[32];
    #pragma unroll
    for (int d0 = 0; d0 < 32; d0 += 8) load8_rt(f32, Wo, tid * 32 + d0, wv + d0);
    const float bov = f32 ? ((const float*)bo)[tid] : b2f_u(((const unsigned short*)bo)[tid]);
    #pragma unroll
    for (int r = 0; r < 4; r++) {
        float acc = bov;
        #pragma unroll
        for (int t = 0; t < 32; t++) acc += sig[r][t] * wv[t];
        size_t oi = ((size_t)ob * 1024 + n0 + r) * DD + tid;
        if (f32) ((float*)out)[oi] = acc;
        else     ((unsigned short*)out)[oi] = f2b(acc);
    }
}

// ---------------------------------------------------------------------------
extern "C" void kernel_launch(void* const* d_in, const int* in_sizes, int n_in,
                              void* d_out, int out_size, void* d_ws, size_t ws_size,
                              hipStream_t stream)
{
    const unsigned short* x = (const unsigned short*)d_in[0];
    const void* Wq  = d_in[1];
    const void* Wk  = d_in[2];
    const void* Wp  = d_in[3];
    const void* bp  = d_in[4];
    const void* Wo  = d_in[5];
    const void* bo  = d_in[6];
    const void* om  = d_in[7];
    const void* cs  = d_in[8];

    char* w = (char*)d_ws;
    unsigned short* Qb  = (unsigned short*)w;
    unsigned short* Kb  = (unsigned short*)(w + (1u << 20));
    float*          PH0 = (float*)(w + (2u << 20));
    unsigned short* SCB = (unsigned short*)(w + (2u << 20) + (256u << 10));
    unsigned int*   flg = (unsigned int*)(w + (4u << 20));

    k_projm<<<288, 256, 0, stream>>>(x, Wq, Wk, Wp, bp, Qb, Kb, PH0, SCB, flg);
    k_mega4<<<512, 256, 0, stream>>>(x, Qb, Kb, PH0, SCB, om, cs,
                                     Wo, bo, d_out, flg);
}